// Round 8
// baseline (2108.879 us; speedup 1.0000x reference)
//
#include <hip/hip_runtime.h>
#include <math.h>

constexpr int Bb = 32, Nn = 2048;
constexpr int S1 = 512, K1 = 48;
constexpr int S2 = 128, K2 = 64;

#define DEVI __device__ __forceinline__

// Exact (non-FMA-contracted) squared distance, matches numpy ((dx^2+dy^2)+dz^2) fp32.
DEVI float sq3(float dx, float dy, float dz) {
    return __fadd_rn(__fadd_rn(__fmul_rn(dx, dx), __fmul_rn(dy, dy)), __fmul_rn(dz, dz));
}

// pc (B,3,N) -> xyz (B,N,3)
__global__ void k_transpose(const float* __restrict__ pc, float* __restrict__ xyz) {
    int i = blockIdx.x * blockDim.x + threadIdx.x;
    if (i >= Bb * Nn) return;
    int b = i / Nn;
    const float* s = pc + (size_t)b * 3 * Nn + (i % Nn);
    float* d = xyz + (size_t)i * 3;
    d[0] = s[0];
    d[1] = s[Nn];
    d[2] = s[2 * Nn];
}

// Transpose stage-2 weights into [c][o] layout (one-time, tiny).
__global__ void k_wtrans(const float* __restrict__ w2a, const float* __restrict__ w2b,
                         float* __restrict__ w2aT, float* __restrict__ w2bT) {
    int i = blockIdx.x * blockDim.x + threadIdx.x;
    if (i < 134 * 128) {
        int c = i >> 7, o = i & 127;
        w2aT[i] = w2a[(size_t)o * 134 + c];
    }
    if (i < 128 * 512) {
        int c = i >> 9, o = i & 511;
        w2bT[i] = w2b[(size_t)o * 128 + c];
    }
}

// FPS, latency-optimized: one block (4 waves) per batch; dist in registers;
// wave shuffle argmax + 4-entry cross-wave exchange. Bitwise-identical selection.
template <int PTS>
__global__ __launch_bounds__(256)
void k_fps_fast(const float* __restrict__ pts, int npoint, float* __restrict__ sel) {
    constexpr int N = PTS * 256;
    __shared__ float px[N], py[N], pz[N];
    __shared__ float rv[4];
    __shared__ int ri[4];
    int b = blockIdx.x, t = threadIdx.x;
    const float* base = pts + (size_t)b * N * 3;
    float dist[PTS];
    #pragma unroll
    for (int i = 0; i < PTS; ++i) {
        int j = i * 256 + t;
        px[j] = base[j * 3 + 0];
        py[j] = base[j * 3 + 1];
        pz[j] = base[j * 3 + 2];
        dist[i] = 1e10f;
    }
    if (t == 0) {
        float* o = sel + (size_t)b * npoint * 3;
        o[0] = base[0]; o[1] = base[1]; o[2] = base[2];
    }
    __syncthreads();
    float lx = px[0], ly = py[0], lz = pz[0];
    for (int it = 1; it < npoint; ++it) {
        float bv = -1.0f;
        int bi = 0;
        #pragma unroll
        for (int i = 0; i < PTS; ++i) {
            int j = i * 256 + t;
            float d = sq3(px[j] - lx, py[j] - ly, pz[j] - lz);
            float dd = fminf(dist[i], d);
            dist[i] = dd;
            if (dd > bv) { bv = dd; bi = j; }  // ascending j per lane: strict > = first occurrence
        }
        #pragma unroll
        for (int off = 32; off > 0; off >>= 1) {
            float ov = __shfl_down(bv, off);
            int oi = __shfl_down(bi, off);
            if (ov > bv || (ov == bv && oi < bi)) { bv = ov; bi = oi; }
        }
        __syncthreads();
        if ((t & 63) == 0) { rv[t >> 6] = bv; ri[t >> 6] = bi; }
        __syncthreads();
        float v0 = rv[0];
        int i0 = ri[0];
        #pragma unroll
        for (int w = 1; w < 4; ++w) {
            float vw = rv[w]; int iw = ri[w];
            if (vw > v0 || (vw == v0 && iw < i0)) { v0 = vw; i0 = iw; }
        }
        lx = px[i0]; ly = py[i0]; lz = pz[i0];
        if (t == 0) {
            float* o = sel + ((size_t)b * npoint + it) * 3;
            o[0] = lx; o[1] = ly; o[2] = lz;
        }
    }
}

// Ball query, one wave per center: ballot + popcount prefix, ascending order.
__global__ void k_ballquery_w(const float* __restrict__ src, const float* __restrict__ ctr,
                              int n, int m, int nsample, float r2, int* __restrict__ out) {
    int wid = blockIdx.x * (blockDim.x >> 6) + (threadIdx.x >> 6);
    int lane = threadIdx.x & 63;
    if (wid >= Bb * m) return;
    int b = wid / m;
    const float* sb = src + (size_t)b * n * 3;
    float cx = ctr[(size_t)wid * 3 + 0];
    float cy = ctr[(size_t)wid * 3 + 1];
    float cz = ctr[(size_t)wid * 3 + 2];
    int* ob = out + (size_t)wid * nsample;
    int cnt = 0, first = 0;
    for (int j0 = 0; j0 < n && cnt < nsample; j0 += 64) {
        int j = j0 + lane;
        float d2 = sq3(sb[j * 3 + 0] - cx, sb[j * 3 + 1] - cy, sb[j * 3 + 2] - cz);
        bool hit = d2 < r2;
        unsigned long long mask = __ballot(hit);
        if (cnt == 0 && mask) first = j0 + __ffsll(mask) - 1;
        int pos = cnt + __popcll(mask & ((1ull << lane) - 1ull));
        if (hit && pos < nsample) ob[pos] = j;
        cnt += __popcll(mask);
    }
    if (cnt < nsample)
        for (int k = cnt + lane; k < nsample; k += 64) ob[k] = first;
}

__global__ void k_zero_stats(double* dsum, double* dsq, int O) {
    int i = blockIdx.x * blockDim.x + threadIdx.x;
    if (i < O) { dsum[i] = 0.0; dsq[i] = 0.0; }
}

__global__ void k_finalize(const double* __restrict__ dsum, const double* __restrict__ dsq,
                           const float* __restrict__ g, float* __restrict__ mean,
                           float* __restrict__ scale, int O, double inv_count) {
    int o = blockIdx.x * blockDim.x + threadIdx.x;
    if (o < O) {
        double m = dsum[o] * inv_count;
        double v = dsq[o] * inv_count - m * m;
        mean[o] = (float)m;
        scale[o] = (float)((double)g[o] / sqrt(v + 1e-5));
    }
}

// Apply norm+relu to pooled minmax (in-place capable).
__global__ void k_applyMM(const float* __restrict__ gmx, const float* __restrict__ gmn,
                          const float* __restrict__ m, const float* __restrict__ s,
                          const float* __restrict__ beta, float* __restrict__ f,
                          long long total, int O) {
    long long i = (long long)blockIdx.x * blockDim.x + threadIdx.x;
    if (i >= total) return;
    int o = (int)(i % O);
    float sc = s[o];
    float pick = (sc >= 0.f) ? gmx[i] : gmn[i];
    f[i] = fmaxf((pick - m[o]) * sc + beta[o], 0.f);
}

// ---------------- Stage 1 ----------------
// y1a is LINEAR in the 6-dim feature: stats from 27 fused moments (S, G=sum ffT).
__global__ __launch_bounds__(256)
void k_s1_moments(const float* __restrict__ xyz, const float* __restrict__ xyz1,
                  const int* __restrict__ ni1, double* __restrict__ dG) {
    __shared__ float wsum[4][27];
    int t = threadIdx.x;
    float p[27];
    #pragma unroll
    for (int v = 0; v < 27; ++v) p[v] = 0.f;
    const int total = Bb * S1 * K1;
    for (int i = blockIdx.x * 256 + t; i < total; i += gridDim.x * 256) {
        int bs = i / K1;
        int b = bs >> 9;
        int j = ni1[i];
        const float* g = xyz + ((size_t)b * Nn + j) * 3;
        float cx = xyz1[bs * 3 + 0], cy = xyz1[bs * 3 + 1], cz = xyz1[bs * 3 + 2];
        float f[6] = {g[0] - cx, g[1] - cy, g[2] - cz, g[0], g[1], g[2]};
        int idx = 6;
        #pragma unroll
        for (int c = 0; c < 6; ++c) {
            p[c] += f[c];
            #pragma unroll
            for (int d = c; d < 6; ++d) p[idx++] += f[c] * f[d];
        }
    }
    #pragma unroll
    for (int v = 0; v < 27; ++v)
        #pragma unroll
        for (int off = 32; off > 0; off >>= 1)
            p[v] += __shfl_down(p[v], off);
    if ((t & 63) == 0)
        #pragma unroll
        for (int v = 0; v < 27; ++v) wsum[t >> 6][v] = p[v];
    __syncthreads();
    if (t < 27) {
        double s = (double)wsum[0][t] + wsum[1][t] + wsum[2][t] + wsum[3][t];
        atomicAdd(&dG[t], s);
    }
}

__global__ void k_fin1a(const double* __restrict__ dG, const float* __restrict__ w1a,
                        const float* __restrict__ g1a, float* __restrict__ m1a,
                        float* __restrict__ s1a, double inv_n) {
    int o = threadIdx.x;
    if (o >= 64) return;
    double w[6];
    #pragma unroll
    for (int c = 0; c < 6; ++c) w[c] = (double)w1a[o * 6 + c];
    double mean = 0.0;
    #pragma unroll
    for (int c = 0; c < 6; ++c) mean += w[c] * dG[c];
    mean *= inv_n;
    double ey2 = 0.0;
    int idx = 6;
    #pragma unroll
    for (int c = 0; c < 6; ++c)
        #pragma unroll
        for (int d = c; d < 6; ++d, ++idx) {
            double term = w[c] * w[d] * dG[idx];
            ey2 += (d == c) ? term : 2.0 * term;
        }
    ey2 *= inv_n;
    double var = ey2 - mean * mean;
    m1a[o] = (float)mean;
    s1a[o] = (float)((double)g1a[o] / sqrt(var + 1e-5));
}

// Main stage-1: TWO bs per 512-thread block sharing wT.
constexpr int LDK1 = 50;  // 48 k + 2 pad
__global__ __launch_bounds__(512)
void k_s1_main(const float* __restrict__ xyz, const float* __restrict__ xyz1,
               const int* __restrict__ ni1, const float* __restrict__ w1a,
               const float* __restrict__ m1a, const float* __restrict__ s1a,
               const float* __restrict__ beta1a, const float* __restrict__ w1b,
               double* __restrict__ dsum, double* __restrict__ dsq,
               float* __restrict__ gmx, float* __restrict__ gmn) {
    __shared__ float x1T[2 * 64 * LDK1];  // 25.6 KB [half][c][k]
    __shared__ float wT[64 * 128];        // 32 KB   [c][o]
    int t = threadIdx.x;
    int half = t >> 8, tl = t & 255;
    float* x1h = x1T + half * 64 * LDK1;
    int og = tl >> 3, kg = tl & 7;        // 32 o-groups x 8 k-groups
    int o0 = og * 4, k0 = kg * 6;
    for (int idx = t; idx < 64 * 128; idx += 512)
        wT[idx] = w1b[(size_t)(idx & 127) * 64 + (idx >> 7)];
    __syncthreads();
    float lsB[4] = {0.f, 0.f, 0.f, 0.f}, lqB[4] = {0.f, 0.f, 0.f, 0.f};
    for (int p = blockIdx.x; p < Bb * S1 / 2; p += gridDim.x) {
        int bs = p * 2 + half;
        int b = bs >> 9;
        float cx = xyz1[bs * 3 + 0], cy = xyz1[bs * 3 + 1], cz = xyz1[bs * 3 + 2];
        #pragma unroll
        for (int i = 0; i < 12; ++i) {
            int idx = tl + i * 256;
            int k = idx >> 6, c = idx & 63;
            int j = ni1[bs * K1 + k];
            const float* g = xyz + ((size_t)b * Nn + j) * 3;
            float gx = g[0], gy = g[1], gz = g[2];
            const float* w = w1a + c * 6;
            float y = (gx - cx) * w[0] + (gy - cy) * w[1] + (gz - cz) * w[2]
                    + gx * w[3] + gy * w[4] + gz * w[5];
            x1h[c * LDK1 + k] = fmaxf((y - m1a[c]) * s1a[c] + beta1a[c], 0.f);
        }
        __syncthreads();
        float acc[24];
        #pragma unroll
        for (int i = 0; i < 24; ++i) acc[i] = 0.f;
        for (int c = 0; c < 64; ++c) {
            float4 wv = *(const float4*)&wT[c * 128 + o0];
            float2 xa = *(const float2*)&x1h[c * LDK1 + k0];
            float2 xb = *(const float2*)&x1h[c * LDK1 + k0 + 2];
            float2 xc = *(const float2*)&x1h[c * LDK1 + k0 + 4];
            float xs[6] = {xa.x, xa.y, xb.x, xb.y, xc.x, xc.y};
            float ws[4] = {wv.x, wv.y, wv.z, wv.w};
            #pragma unroll
            for (int i = 0; i < 4; ++i)
                #pragma unroll
                for (int j = 0; j < 6; ++j)
                    acc[i * 6 + j] = fmaf(ws[i], xs[j], acc[i * 6 + j]);
        }
        float mx[4], mn[4];
        #pragma unroll
        for (int i = 0; i < 4; ++i) {
            mx[i] = -1e30f; mn[i] = 1e30f;
            #pragma unroll
            for (int j = 0; j < 6; ++j) {
                float y = acc[i * 6 + j];
                lsB[i] += y; lqB[i] += y * y;
                mx[i] = fmaxf(mx[i], y); mn[i] = fminf(mn[i], y);
            }
        }
        #pragma unroll
        for (int off = 4; off > 0; off >>= 1)
            #pragma unroll
            for (int i = 0; i < 4; ++i) {
                mx[i] = fmaxf(mx[i], __shfl_down(mx[i], off));
                mn[i] = fminf(mn[i], __shfl_down(mn[i], off));
            }
        if (kg == 0) {
            *(float4*)&gmx[(size_t)bs * 128 + o0] = make_float4(mx[0], mx[1], mx[2], mx[3]);
            *(float4*)&gmn[(size_t)bs * 128 + o0] = make_float4(mn[0], mn[1], mn[2], mn[3]);
        }
        __syncthreads();
    }
    #pragma unroll
    for (int off = 4; off > 0; off >>= 1)
        #pragma unroll
        for (int i = 0; i < 4; ++i) {
            lsB[i] += __shfl_down(lsB[i], off);
            lqB[i] += __shfl_down(lqB[i], off);
        }
    if (kg == 0)
        #pragma unroll
        for (int i = 0; i < 4; ++i) {
            atomicAdd(&dsum[o0 + i], (double)lsB[i]);
            atomicAdd(&dsq[o0 + i], (double)lqB[i]);
        }
}

// ---------------- Stage 2 ----------------
constexpr int LDK2 = 68;  // 64 k + 4 pad

DEVI void s2_gatherT(int t, int bs, const float* xyz1, const float* xyz2,
                     const int* ni2, const float* f1, float* xT) {
    int b = bs >> 7;
    float cx = xyz2[bs * 3 + 0], cy = xyz2[bs * 3 + 1], cz = xyz2[bs * 3 + 2];
    for (int idx = t; idx < K2 * 134; idx += 512) {
        int k = idx / 134, c = idx - k * 134;
        int j = ni2[bs * K2 + k];
        const float* p1 = xyz1 + ((size_t)b * S1 + j) * 3;
        float v;
        if (c < 3)      v = p1[c] - (c == 0 ? cx : (c == 1 ? cy : cz));
        else if (c < 6) v = p1[c - 3];
        else            v = f1[((size_t)b * S1 + j) * 128 + (c - 6)];
        xT[c * LDK2 + k] = v;
    }
}

// Stats of y2a (C=134 -> O=128). Tile 4o x 4k; LDS 36.4K -> 4 blk/CU; 64-VGPR cap ok.
__global__ __launch_bounds__(512, 4)
void k_s2_statsA(const float* __restrict__ xyz1, const float* __restrict__ xyz2,
                 const int* __restrict__ ni2, const float* __restrict__ f1,
                 const float* __restrict__ w2aT,
                 double* __restrict__ dsum, double* __restrict__ dsq) {
    __shared__ float xT[134 * LDK2];   // 36.4 KB
    int t = threadIdx.x;
    int og = t >> 4, kg = t & 15;      // 32 x 16
    int o0 = og * 4, k0 = kg * 4;
    float ls[4] = {0.f, 0.f, 0.f, 0.f}, lq[4] = {0.f, 0.f, 0.f, 0.f};
    for (int bs = blockIdx.x; bs < Bb * S2; bs += gridDim.x) {
        __syncthreads();
        s2_gatherT(t, bs, xyz1, xyz2, ni2, f1, xT);
        __syncthreads();
        float acc[16];
        #pragma unroll
        for (int i = 0; i < 16; ++i) acc[i] = 0.f;
        for (int c = 0; c < 134; ++c) {
            float4 wv = *(const float4*)&w2aT[c * 128 + o0];
            float4 xv = *(const float4*)&xT[c * LDK2 + k0];
            float ws[4] = {wv.x, wv.y, wv.z, wv.w};
            float xs[4] = {xv.x, xv.y, xv.z, xv.w};
            #pragma unroll
            for (int i = 0; i < 4; ++i)
                #pragma unroll
                for (int j = 0; j < 4; ++j)
                    acc[i * 4 + j] = fmaf(ws[i], xs[j], acc[i * 4 + j]);
        }
        #pragma unroll
        for (int i = 0; i < 4; ++i)
            #pragma unroll
            for (int j = 0; j < 4; ++j) {
                float y = acc[i * 4 + j];
                ls[i] += y; lq[i] += y * y;
            }
    }
    #pragma unroll
    for (int off = 8; off > 0; off >>= 1)
        #pragma unroll
        for (int i = 0; i < 4; ++i) {
            ls[i] += __shfl_down(ls[i], off);
            lq[i] += __shfl_down(lq[i], off);
        }
    if (kg == 0)
        #pragma unroll
        for (int i = 0; i < 4; ++i) {
            atomicAdd(&dsum[o0 + i], (double)ls[i]);
            atomicAdd(&dsq[o0 + i], (double)lq[i]);
        }
}

// Main stage-2. __launch_bounds__(512, 2): measured (r6/r7) HIP treats arg2 as min
// BLOCKS/CU — (512,4) capped VGPR at 64 (accB spilled, 620us); plain (512) chose 68
// (777us). LDS (71.7 KB) caps at 2 blocks anyway -> (512,2) gives 128-VGPR budget.
// B-tile 8o x 8k: halves LDS bytes/FMA vs 4o x 16k (0.5 B/FMA), breaking the
// LDS-BW = VALU tie observed at 69% VALUBusy.
__global__ __launch_bounds__(512, 2)
void k_s2_main(const float* __restrict__ xyz1, const float* __restrict__ xyz2,
               const int* __restrict__ ni2, const float* __restrict__ f1,
               const float* __restrict__ w2aT,
               const float* __restrict__ m2a, const float* __restrict__ s2a,
               const float* __restrict__ beta2a, const float* __restrict__ w2bT,
               double* __restrict__ dsum, double* __restrict__ dsq,
               float* __restrict__ gmx, float* __restrict__ gmn) {
    __shared__ float xT[134 * LDK2];    // 36.4 KB gather tile
    __shared__ float x2T[128 * LDK2];   // 34.8 KB x2 [c2][k]
    int t = threadIdx.x;
    int ogA = t >> 4, kgA = t & 15;    // A: 4o x 4k
    int o0A = ogA * 4, k0A = kgA * 4;
    int ogB = t >> 3, kgB = t & 7;     // B: 8o x 8k
    int o0B = ogB * 8, k0B = kgB * 8;
    float lsB[8], lqB[8];
    #pragma unroll
    for (int i = 0; i < 8; ++i) { lsB[i] = 0.f; lqB[i] = 0.f; }
    for (int bs = blockIdx.x; bs < Bb * S2; bs += gridDim.x) {
        __syncthreads();
        s2_gatherT(t, bs, xyz1, xyz2, ni2, f1, xT);
        __syncthreads();
        // A: y2a tile
        float acc[16];
        #pragma unroll
        for (int i = 0; i < 16; ++i) acc[i] = 0.f;
        for (int c = 0; c < 134; ++c) {
            float4 wv = *(const float4*)&w2aT[c * 128 + o0A];
            float4 xv = *(const float4*)&xT[c * LDK2 + k0A];
            float ws[4] = {wv.x, wv.y, wv.z, wv.w};
            float xs[4] = {xv.x, xv.y, xv.z, xv.w};
            #pragma unroll
            for (int i = 0; i < 4; ++i)
                #pragma unroll
                for (int j = 0; j < 4; ++j)
                    acc[i * 4 + j] = fmaf(ws[i], xs[j], acc[i * 4 + j]);
        }
        float4 mam = *(const float4*)&m2a[o0A];
        float4 sam = *(const float4*)&s2a[o0A];
        float4 bam = *(const float4*)&beta2a[o0A];
        float ma[4] = {mam.x, mam.y, mam.z, mam.w};
        float sa[4] = {sam.x, sam.y, sam.z, sam.w};
        float ba[4] = {bam.x, bam.y, bam.z, bam.w};
        #pragma unroll
        for (int i = 0; i < 4; ++i) {
            float4 v;
            v.x = fmaxf((acc[i * 4 + 0] - ma[i]) * sa[i] + ba[i], 0.f);
            v.y = fmaxf((acc[i * 4 + 1] - ma[i]) * sa[i] + ba[i], 0.f);
            v.z = fmaxf((acc[i * 4 + 2] - ma[i]) * sa[i] + ba[i], 0.f);
            v.w = fmaxf((acc[i * 4 + 3] - ma[i]) * sa[i] + ba[i], 0.f);
            *(float4*)&x2T[(o0A + i) * LDK2 + k0A] = v;
        }
        __syncthreads();
        // B: y2b tile 8o x 8k; w2bT global broadcast (L2-hot)
        float accB[64];
        #pragma unroll
        for (int i = 0; i < 64; ++i) accB[i] = 0.f;
        for (int c = 0; c < 128; ++c) {
            const float* wr = &w2bT[c * 512 + o0B];
            float4 w0 = *(const float4*)(wr);
            float4 w1 = *(const float4*)(wr + 4);
            const float* xr = &x2T[c * LDK2 + k0B];
            float4 x0 = *(const float4*)(xr);
            float4 x1 = *(const float4*)(xr + 4);
            float ws[8] = {w0.x, w0.y, w0.z, w0.w, w1.x, w1.y, w1.z, w1.w};
            float xs[8] = {x0.x, x0.y, x0.z, x0.w, x1.x, x1.y, x1.z, x1.w};
            #pragma unroll
            for (int i = 0; i < 8; ++i)
                #pragma unroll
                for (int j = 0; j < 8; ++j)
                    accB[i * 8 + j] = fmaf(ws[i], xs[j], accB[i * 8 + j]);
        }
        float mxB[8], mnB[8];
        #pragma unroll
        for (int i = 0; i < 8; ++i) {
            mxB[i] = -1e30f; mnB[i] = 1e30f;
            #pragma unroll
            for (int j = 0; j < 8; ++j) {
                float y = accB[i * 8 + j];
                lsB[i] += y; lqB[i] += y * y;
                mxB[i] = fmaxf(mxB[i], y); mnB[i] = fminf(mnB[i], y);
            }
        }
        #pragma unroll
        for (int off = 4; off > 0; off >>= 1)
            #pragma unroll
            for (int i = 0; i < 8; ++i) {
                mxB[i] = fmaxf(mxB[i], __shfl_down(mxB[i], off));
                mnB[i] = fminf(mnB[i], __shfl_down(mnB[i], off));
            }
        if (kgB == 0) {
            *(float4*)&gmx[(size_t)bs * 512 + o0B] = make_float4(mxB[0], mxB[1], mxB[2], mxB[3]);
            *(float4*)&gmx[(size_t)bs * 512 + o0B + 4] = make_float4(mxB[4], mxB[5], mxB[6], mxB[7]);
            *(float4*)&gmn[(size_t)bs * 512 + o0B] = make_float4(mnB[0], mnB[1], mnB[2], mnB[3]);
            *(float4*)&gmn[(size_t)bs * 512 + o0B + 4] = make_float4(mnB[4], mnB[5], mnB[6], mnB[7]);
        }
    }
    #pragma unroll
    for (int off = 4; off > 0; off >>= 1)
        #pragma unroll
        for (int i = 0; i < 8; ++i) {
            lsB[i] += __shfl_down(lsB[i], off);
            lqB[i] += __shfl_down(lqB[i], off);
        }
    if (kgB == 0)
        #pragma unroll
        for (int i = 0; i < 8; ++i) {
            atomicAdd(&dsum[o0B + i], (double)lsB[i]);
            atomicAdd(&dsq[o0B + i], (double)lqB[i]);
        }
}

// ---------------- Stage 3 ----------------
constexpr int X3_LD = 520;

__global__ __launch_bounds__(512)
void k_s3(const float* __restrict__ xyz2, const float* __restrict__ f2,
          const float* __restrict__ w3, double* __restrict__ dsum,
          double* __restrict__ dsq, float* __restrict__ gmx, float* __restrict__ gmn) {
    __shared__ float xt[16 * X3_LD];  // 33.3 KB
    int b = blockIdx.x >> 3, kc = blockIdx.x & 7;
    int t = threadIdx.x;  // = o
    for (int idx = t; idx < 16 * X3_LD; idx += 512) {
        int rr = idx / X3_LD, c = idx - rr * X3_LD;
        int row = b * S2 + kc * 16 + rr;
        float v;
        if (c < 3)        v = xyz2[row * 3 + c];
        else if (c < 515) v = f2[(size_t)row * 512 + (c - 3)];
        else              v = 0.f;
        xt[idx] = v;
    }
    __syncthreads();
    float acc[16];
    #pragma unroll
    for (int rr = 0; rr < 16; ++rr) acc[rr] = 0.f;
    for (int ct = 0; ct < 16; ++ct) {
        float wr[32];
        #pragma unroll
        for (int i = 0; i < 32; ++i) wr[i] = w3[(size_t)t * 515 + ct * 32 + i];
        #pragma unroll
        for (int rr = 0; rr < 16; ++rr) {
            const float* xr = &xt[rr * X3_LD + ct * 32];
            #pragma unroll
            for (int j = 0; j < 8; ++j) {
                float4 x = *(const float4*)(xr + 4 * j);
                acc[rr] = fmaf(x.x, wr[4 * j + 0], acc[rr]);
                acc[rr] = fmaf(x.y, wr[4 * j + 1], acc[rr]);
                acc[rr] = fmaf(x.z, wr[4 * j + 2], acc[rr]);
                acc[rr] = fmaf(x.w, wr[4 * j + 3], acc[rr]);
            }
        }
    }
    {
        float wr[8];
        #pragma unroll
        for (int i = 0; i < 8; ++i) wr[i] = (i < 3) ? w3[(size_t)t * 515 + 512 + i] : 0.f;
        #pragma unroll
        for (int rr = 0; rr < 16; ++rr) {
            const float* xr = &xt[rr * X3_LD + 512];
            #pragma unroll
            for (int j = 0; j < 2; ++j) {
                float4 x = *(const float4*)(xr + 4 * j);
                acc[rr] = fmaf(x.x, wr[4 * j + 0], acc[rr]);
                acc[rr] = fmaf(x.y, wr[4 * j + 1], acc[rr]);
                acc[rr] = fmaf(x.z, wr[4 * j + 2], acc[rr]);
                acc[rr] = fmaf(x.w, wr[4 * j + 3], acc[rr]);
            }
        }
    }
    float ls = 0.f, lsq = 0.f, mxv = -1e30f, mnv = 1e30f;
    #pragma unroll
    for (int rr = 0; rr < 16; ++rr) {
        float y = acc[rr];
        ls += y; lsq += y * y;
        mxv = fmaxf(mxv, y); mnv = fminf(mnv, y);
    }
    atomicAdd(&dsum[t], (double)ls);
    atomicAdd(&dsq[t], (double)lsq);
    gmx[(size_t)blockIdx.x * 512 + t] = mxv;
    gmn[(size_t)blockIdx.x * 512 + t] = mnv;
}

__global__ void k_apply3(const float* __restrict__ gmx, const float* __restrict__ gmn,
                         const float* __restrict__ m, const float* __restrict__ s,
                         const float* __restrict__ beta, float* __restrict__ out) {
    int i = blockIdx.x * blockDim.x + threadIdx.x;
    if (i >= Bb * 512) return;
    int b = i >> 9, o = i & 511;
    float mx = -1e30f, mn = 1e30f;
    for (int ch = 0; ch < 8; ++ch) {
        mx = fmaxf(mx, gmx[(size_t)(b * 8 + ch) * 512 + o]);
        mn = fminf(mn, gmn[(size_t)(b * 8 + ch) * 512 + o]);
    }
    float sc = s[o];
    float pick = (sc >= 0.f) ? mx : mn;
    out[i] = fmaxf((pick - m[o]) * sc + beta[o], 0.f);
}

static inline size_t align256(size_t x) { return (x + 255) & ~(size_t)255; }

extern "C" void kernel_launch(void* const* d_in, const int* in_sizes, int n_in,
                              void* d_out, int out_size, void* d_ws, size_t ws_size,
                              hipStream_t stream) {
    const float* pc  = (const float*)d_in[0];
    const float* w1a = (const float*)d_in[1];
    const float* g1a = (const float*)d_in[2];
    const float* b1a = (const float*)d_in[3];
    const float* w1b = (const float*)d_in[4];
    const float* g1b = (const float*)d_in[5];
    const float* b1b = (const float*)d_in[6];
    const float* w2a = (const float*)d_in[7];
    const float* g2a = (const float*)d_in[8];
    const float* b2a = (const float*)d_in[9];
    const float* w2b = (const float*)d_in[10];
    const float* g2b = (const float*)d_in[11];
    const float* b2b = (const float*)d_in[12];
    const float* w3  = (const float*)d_in[13];
    const float* g3  = (const float*)d_in[14];
    const float* b3  = (const float*)d_in[15];
    float* out = (float*)d_out;

    char* ws = (char*)d_ws;
    size_t off = 0;
    auto alloc = [&](size_t bytes) { void* p = ws + off; off += align256(bytes); return p; };

    float* xyz   = (float*)alloc(sizeof(float) * Bb * Nn * 3);
    float* xyz1  = (float*)alloc(sizeof(float) * Bb * S1 * 3);
    float* xyz2  = (float*)alloc(sizeof(float) * Bb * S2 * 3);
    int*   ni1   = (int*)alloc(sizeof(int) * Bb * S1 * K1);
    int*   ni2   = (int*)alloc(sizeof(int) * Bb * S2 * K2);
    float* gmx1  = (float*)alloc(sizeof(float) * (size_t)Bb * S1 * 128);  // f1 after apply
    float* gmn1  = (float*)alloc(sizeof(float) * (size_t)Bb * S1 * 128);
    float* gmx2  = (float*)alloc(sizeof(float) * (size_t)Bb * S2 * 512);  // f2 after apply
    float* gmn2  = (float*)alloc(sizeof(float) * (size_t)Bb * S2 * 512);
    float* gmx3  = (float*)alloc(sizeof(float) * 256 * 512);
    float* gmn3  = (float*)alloc(sizeof(float) * 256 * 512);
    float* w2aT  = (float*)alloc(sizeof(float) * 134 * 128);
    float* w2bT  = (float*)alloc(sizeof(float) * 128 * 512);
    double* dsum = (double*)alloc(sizeof(double) * 512);
    double* dsq  = (double*)alloc(sizeof(double) * 512);
    float* m1a = (float*)alloc(sizeof(float) * 64);
    float* s1a = (float*)alloc(sizeof(float) * 64);
    float* m1b = (float*)alloc(sizeof(float) * 128);
    float* s1b = (float*)alloc(sizeof(float) * 128);
    float* m2a = (float*)alloc(sizeof(float) * 128);
    float* s2a = (float*)alloc(sizeof(float) * 128);
    float* m2b = (float*)alloc(sizeof(float) * 512);
    float* s2b = (float*)alloc(sizeof(float) * 512);
    float* m3  = (float*)alloc(sizeof(float) * 512);
    float* s3  = (float*)alloc(sizeof(float) * 512);
    float* f1 = gmx1;  // in-place apply
    float* f2 = gmx2;

    // ---- Stage 1 ----
    k_transpose<<<(Bb * Nn + 255) / 256, 256, 0, stream>>>(pc, xyz);
    k_wtrans<<<256, 256, 0, stream>>>(w2a, w2b, w2aT, w2bT);
    k_fps_fast<8><<<Bb, 256, 0, stream>>>(xyz, S1, xyz1);
    k_ballquery_w<<<(Bb * S1) / 4, 256, 0, stream>>>(xyz, xyz1, Nn, S1, K1,
                                                     (float)(0.23 * 0.23), ni1);
    k_zero_stats<<<2, 256, 0, stream>>>(dsum, dsq, 512);
    k_s1_moments<<<1024, 256, 0, stream>>>(xyz, xyz1, ni1, dsum);
    k_fin1a<<<1, 64, 0, stream>>>(dsum, w1a, g1a, m1a, s1a,
                                  1.0 / ((double)Bb * S1 * K1));
    k_zero_stats<<<2, 256, 0, stream>>>(dsum, dsq, 512);
    k_s1_main<<<1024, 512, 0, stream>>>(xyz, xyz1, ni1, w1a, m1a, s1a, b1a, w1b,
                                        dsum, dsq, gmx1, gmn1);
    k_finalize<<<2, 256, 0, stream>>>(dsum, dsq, g1b, m1b, s1b, 128,
                                      1.0 / ((double)Bb * S1 * K1));
    {
        long long tot = (long long)Bb * S1 * 128;
        k_applyMM<<<(int)((tot + 255) / 256), 256, 0, stream>>>(gmx1, gmn1, m1b, s1b, b1b,
                                                                f1, tot, 128);
    }
    // ---- Stage 2 ----
    k_fps_fast<2><<<Bb, 256, 0, stream>>>(xyz1, S2, xyz2);
    k_ballquery_w<<<(Bb * S2) / 4, 256, 0, stream>>>(xyz1, xyz2, S1, S2, K2,
                                                     (float)(0.32 * 0.32), ni2);
    k_zero_stats<<<2, 256, 0, stream>>>(dsum, dsq, 512);
    k_s2_statsA<<<1024, 512, 0, stream>>>(xyz1, xyz2, ni2, f1, w2aT, dsum, dsq);
    k_finalize<<<2, 256, 0, stream>>>(dsum, dsq, g2a, m2a, s2a, 128,
                                      1.0 / ((double)Bb * S2 * K2));
    k_zero_stats<<<2, 256, 0, stream>>>(dsum, dsq, 512);
    k_s2_main<<<1024, 512, 0, stream>>>(xyz1, xyz2, ni2, f1, w2aT, m2a, s2a, b2a, w2bT,
                                        dsum, dsq, gmx2, gmn2);
    k_finalize<<<2, 256, 0, stream>>>(dsum, dsq, g2b, m2b, s2b, 512,
                                      1.0 / ((double)Bb * S2 * K2));
    {
        long long tot = (long long)Bb * S2 * 512;
        k_applyMM<<<(int)((tot + 255) / 256), 256, 0, stream>>>(gmx2, gmn2, m2b, s2b, b2b,
                                                                f2, tot, 512);
    }
    // ---- Stage 3 ----
    k_zero_stats<<<2, 256, 0, stream>>>(dsum, dsq, 512);
    k_s3<<<256, 512, 0, stream>>>(xyz2, f2, w3, dsum, dsq, gmx3, gmn3);
    k_finalize<<<2, 256, 0, stream>>>(dsum, dsq, g3, m3, s3, 512,
                                      1.0 / ((double)Bb * S2));
    k_apply3<<<(Bb * 512 + 255) / 256, 256, 0, stream>>>(gmx3, gmn3, m3, s3, b3, out);
}

// Round 9
// 1959.439 us; speedup vs baseline: 1.0763x; 1.0763x over previous
//
#include <hip/hip_runtime.h>
#include <math.h>

constexpr int Bb = 32, Nn = 2048;
constexpr int S1 = 512, K1 = 48;
constexpr int S2 = 128, K2 = 64;

#define DEVI __device__ __forceinline__

// Exact (non-FMA-contracted) squared distance, matches numpy ((dx^2+dy^2)+dz^2) fp32.
DEVI float sq3(float dx, float dy, float dz) {
    return __fadd_rn(__fadd_rn(__fmul_rn(dx, dx), __fmul_rn(dy, dy)), __fmul_rn(dz, dz));
}

// pc (B,3,N) -> xyz (B,N,3); also transposes stage-2 weights and zeroes stat arena.
__global__ void k_prep(const float* __restrict__ pc, float* __restrict__ xyz,
                       const float* __restrict__ w2a, const float* __restrict__ w2b,
                       float* __restrict__ w2aT, float* __restrict__ w2bT,
                       double* __restrict__ statz) {
    int i = blockIdx.x * blockDim.x + threadIdx.x;
    if (i < Bb * Nn) {
        int b = i / Nn;
        const float* s = pc + (size_t)b * 3 * Nn + (i % Nn);
        float* d = xyz + (size_t)i * 3;
        d[0] = s[0];
        d[1] = s[Nn];
        d[2] = s[2 * Nn];
    }
    if (i < 134 * 128) {
        int c = i >> 7, o = i & 127;
        w2aT[i] = w2a[(size_t)o * 134 + c];
    }
    if (i < 128 * 512) {
        int c = i >> 9, o = i & 511;
        w2bT[i] = w2b[(size_t)o * 128 + c];
    }
    if (i < 4096) statz[i] = 0.0;
}

// FPS, latency-optimized: one block (4 waves) per batch; dist in registers;
// wave shuffle argmax + 4-entry cross-wave exchange. Bitwise-identical selection.
template <int PTS>
__global__ __launch_bounds__(256)
void k_fps_fast(const float* __restrict__ pts, int npoint, float* __restrict__ sel) {
    constexpr int N = PTS * 256;
    __shared__ float px[N], py[N], pz[N];
    __shared__ float rv[4];
    __shared__ int ri[4];
    int b = blockIdx.x, t = threadIdx.x;
    const float* base = pts + (size_t)b * N * 3;
    float dist[PTS];
    #pragma unroll
    for (int i = 0; i < PTS; ++i) {
        int j = i * 256 + t;
        px[j] = base[j * 3 + 0];
        py[j] = base[j * 3 + 1];
        pz[j] = base[j * 3 + 2];
        dist[i] = 1e10f;
    }
    if (t == 0) {
        float* o = sel + (size_t)b * npoint * 3;
        o[0] = base[0]; o[1] = base[1]; o[2] = base[2];
    }
    __syncthreads();
    float lx = px[0], ly = py[0], lz = pz[0];
    for (int it = 1; it < npoint; ++it) {
        float bv = -1.0f;
        int bi = 0;
        #pragma unroll
        for (int i = 0; i < PTS; ++i) {
            int j = i * 256 + t;
            float d = sq3(px[j] - lx, py[j] - ly, pz[j] - lz);
            float dd = fminf(dist[i], d);
            dist[i] = dd;
            if (dd > bv) { bv = dd; bi = j; }  // ascending j per lane: strict > = first occurrence
        }
        #pragma unroll
        for (int off = 32; off > 0; off >>= 1) {
            float ov = __shfl_down(bv, off);
            int oi = __shfl_down(bi, off);
            if (ov > bv || (ov == bv && oi < bi)) { bv = ov; bi = oi; }
        }
        __syncthreads();
        if ((t & 63) == 0) { rv[t >> 6] = bv; ri[t >> 6] = bi; }
        __syncthreads();
        float v0 = rv[0];
        int i0 = ri[0];
        #pragma unroll
        for (int w = 1; w < 4; ++w) {
            float vw = rv[w]; int iw = ri[w];
            if (vw > v0 || (vw == v0 && iw < i0)) { v0 = vw; i0 = iw; }
        }
        lx = px[i0]; ly = py[i0]; lz = pz[i0];
        if (t == 0) {
            float* o = sel + ((size_t)b * npoint + it) * 3;
            o[0] = lx; o[1] = ly; o[2] = lz;
        }
    }
}

// Ball query, one wave per center: ballot + popcount prefix, ascending order.
__global__ void k_ballquery_w(const float* __restrict__ src, const float* __restrict__ ctr,
                              int n, int m, int nsample, float r2, int* __restrict__ out) {
    int wid = blockIdx.x * (blockDim.x >> 6) + (threadIdx.x >> 6);
    int lane = threadIdx.x & 63;
    if (wid >= Bb * m) return;
    int b = wid / m;
    const float* sb = src + (size_t)b * n * 3;
    float cx = ctr[(size_t)wid * 3 + 0];
    float cy = ctr[(size_t)wid * 3 + 1];
    float cz = ctr[(size_t)wid * 3 + 2];
    int* ob = out + (size_t)wid * nsample;
    int cnt = 0, first = 0;
    for (int j0 = 0; j0 < n && cnt < nsample; j0 += 64) {
        int j = j0 + lane;
        float d2 = sq3(sb[j * 3 + 0] - cx, sb[j * 3 + 1] - cy, sb[j * 3 + 2] - cz);
        bool hit = d2 < r2;
        unsigned long long mask = __ballot(hit);
        if (cnt == 0 && mask) first = j0 + __ffsll(mask) - 1;
        int pos = cnt + __popcll(mask & ((1ull << lane) - 1ull));
        if (hit && pos < nsample) ob[pos] = j;
        cnt += __popcll(mask);
    }
    if (cnt < nsample)
        for (int k = cnt + lane; k < nsample; k += 64) ob[k] = first;
}

__global__ void k_finalize(const double* __restrict__ dsum, const double* __restrict__ dsq,
                           const float* __restrict__ g, float* __restrict__ mean,
                           float* __restrict__ scale, int O, double inv_count) {
    int o = blockIdx.x * blockDim.x + threadIdx.x;
    if (o < O) {
        double m = dsum[o] * inv_count;
        double v = dsq[o] * inv_count - m * m;
        mean[o] = (float)m;
        scale[o] = (float)((double)g[o] / sqrt(v + 1e-5));
    }
}

// Apply norm+relu to pooled minmax (in-place capable).
__global__ void k_applyMM(const float* __restrict__ gmx, const float* __restrict__ gmn,
                          const float* __restrict__ m, const float* __restrict__ s,
                          const float* __restrict__ beta, float* __restrict__ f,
                          long long total, int O) {
    long long i = (long long)blockIdx.x * blockDim.x + threadIdx.x;
    if (i >= total) return;
    int o = (int)(i % O);
    float sc = s[o];
    float pick = (sc >= 0.f) ? gmx[i] : gmn[i];
    f[i] = fmaxf((pick - m[o]) * sc + beta[o], 0.f);
}

// ---------------- Stage 1 ----------------
// y1a is LINEAR in the 6-dim feature: stats from 27 fused moments (S, G=sum ffT).
__global__ __launch_bounds__(256)
void k_s1_moments(const float* __restrict__ xyz, const float* __restrict__ xyz1,
                  const int* __restrict__ ni1, double* __restrict__ dG) {
    __shared__ float wsum[4][27];
    int t = threadIdx.x;
    float p[27];
    #pragma unroll
    for (int v = 0; v < 27; ++v) p[v] = 0.f;
    const int total = Bb * S1 * K1;
    for (int i = blockIdx.x * 256 + t; i < total; i += gridDim.x * 256) {
        int bs = i / K1;
        int b = bs >> 9;
        int j = ni1[i];
        const float* g = xyz + ((size_t)b * Nn + j) * 3;
        float cx = xyz1[bs * 3 + 0], cy = xyz1[bs * 3 + 1], cz = xyz1[bs * 3 + 2];
        float f[6] = {g[0] - cx, g[1] - cy, g[2] - cz, g[0], g[1], g[2]};
        int idx = 6;
        #pragma unroll
        for (int c = 0; c < 6; ++c) {
            p[c] += f[c];
            #pragma unroll
            for (int d = c; d < 6; ++d) p[idx++] += f[c] * f[d];
        }
    }
    #pragma unroll
    for (int v = 0; v < 27; ++v)
        #pragma unroll
        for (int off = 32; off > 0; off >>= 1)
            p[v] += __shfl_down(p[v], off);
    if ((t & 63) == 0)
        #pragma unroll
        for (int v = 0; v < 27; ++v) wsum[t >> 6][v] = p[v];
    __syncthreads();
    if (t < 27) {
        double s = (double)wsum[0][t] + wsum[1][t] + wsum[2][t] + wsum[3][t];
        atomicAdd(&dG[t], s);
    }
}

__global__ void k_fin1a(const double* __restrict__ dG, const float* __restrict__ w1a,
                        const float* __restrict__ g1a, float* __restrict__ m1a,
                        float* __restrict__ s1a, double inv_n) {
    int o = threadIdx.x;
    if (o >= 64) return;
    double w[6];
    #pragma unroll
    for (int c = 0; c < 6; ++c) w[c] = (double)w1a[o * 6 + c];
    double mean = 0.0;
    #pragma unroll
    for (int c = 0; c < 6; ++c) mean += w[c] * dG[c];
    mean *= inv_n;
    double ey2 = 0.0;
    int idx = 6;
    #pragma unroll
    for (int c = 0; c < 6; ++c)
        #pragma unroll
        for (int d = c; d < 6; ++d, ++idx) {
            double term = w[c] * w[d] * dG[idx];
            ey2 += (d == c) ? term : 2.0 * term;
        }
    ey2 *= inv_n;
    double var = ey2 - mean * mean;
    m1a[o] = (float)mean;
    s1a[o] = (float)((double)g1a[o] / sqrt(var + 1e-5));
}

// Main stage-1: TWO bs per 512-thread block sharing wT.
constexpr int LDK1 = 50;  // 48 k + 2 pad
__global__ __launch_bounds__(512)
void k_s1_main(const float* __restrict__ xyz, const float* __restrict__ xyz1,
               const int* __restrict__ ni1, const float* __restrict__ w1a,
               const float* __restrict__ m1a, const float* __restrict__ s1a,
               const float* __restrict__ beta1a, const float* __restrict__ w1b,
               double* __restrict__ dsum, double* __restrict__ dsq,
               float* __restrict__ gmx, float* __restrict__ gmn) {
    __shared__ float x1T[2 * 64 * LDK1];  // 25.6 KB [half][c][k]
    __shared__ float wT[64 * 128];        // 32 KB   [c][o]
    int t = threadIdx.x;
    int half = t >> 8, tl = t & 255;
    float* x1h = x1T + half * 64 * LDK1;
    int og = tl >> 3, kg = tl & 7;        // 32 o-groups x 8 k-groups
    int o0 = og * 4, k0 = kg * 6;
    for (int idx = t; idx < 64 * 128; idx += 512)
        wT[idx] = w1b[(size_t)(idx & 127) * 64 + (idx >> 7)];
    __syncthreads();
    float lsB[4] = {0.f, 0.f, 0.f, 0.f}, lqB[4] = {0.f, 0.f, 0.f, 0.f};
    for (int p = blockIdx.x; p < Bb * S1 / 2; p += gridDim.x) {
        int bs = p * 2 + half;
        int b = bs >> 9;
        float cx = xyz1[bs * 3 + 0], cy = xyz1[bs * 3 + 1], cz = xyz1[bs * 3 + 2];
        #pragma unroll
        for (int i = 0; i < 12; ++i) {
            int idx = tl + i * 256;
            int k = idx >> 6, c = idx & 63;
            int j = ni1[bs * K1 + k];
            const float* g = xyz + ((size_t)b * Nn + j) * 3;
            float gx = g[0], gy = g[1], gz = g[2];
            const float* w = w1a + c * 6;
            float y = (gx - cx) * w[0] + (gy - cy) * w[1] + (gz - cz) * w[2]
                    + gx * w[3] + gy * w[4] + gz * w[5];
            x1h[c * LDK1 + k] = fmaxf((y - m1a[c]) * s1a[c] + beta1a[c], 0.f);
        }
        __syncthreads();
        float acc[24];
        #pragma unroll
        for (int i = 0; i < 24; ++i) acc[i] = 0.f;
        for (int c = 0; c < 64; ++c) {
            float4 wv = *(const float4*)&wT[c * 128 + o0];
            float2 xa = *(const float2*)&x1h[c * LDK1 + k0];
            float2 xb = *(const float2*)&x1h[c * LDK1 + k0 + 2];
            float2 xc = *(const float2*)&x1h[c * LDK1 + k0 + 4];
            float xs[6] = {xa.x, xa.y, xb.x, xb.y, xc.x, xc.y};
            float ws[4] = {wv.x, wv.y, wv.z, wv.w};
            #pragma unroll
            for (int i = 0; i < 4; ++i)
                #pragma unroll
                for (int j = 0; j < 6; ++j)
                    acc[i * 6 + j] = fmaf(ws[i], xs[j], acc[i * 6 + j]);
        }
        float mx[4], mn[4];
        #pragma unroll
        for (int i = 0; i < 4; ++i) {
            mx[i] = -1e30f; mn[i] = 1e30f;
            #pragma unroll
            for (int j = 0; j < 6; ++j) {
                float y = acc[i * 6 + j];
                lsB[i] += y; lqB[i] += y * y;
                mx[i] = fmaxf(mx[i], y); mn[i] = fminf(mn[i], y);
            }
        }
        #pragma unroll
        for (int off = 4; off > 0; off >>= 1)
            #pragma unroll
            for (int i = 0; i < 4; ++i) {
                mx[i] = fmaxf(mx[i], __shfl_down(mx[i], off));
                mn[i] = fminf(mn[i], __shfl_down(mn[i], off));
            }
        if (kg == 0) {
            *(float4*)&gmx[(size_t)bs * 128 + o0] = make_float4(mx[0], mx[1], mx[2], mx[3]);
            *(float4*)&gmn[(size_t)bs * 128 + o0] = make_float4(mn[0], mn[1], mn[2], mn[3]);
        }
        __syncthreads();
    }
    #pragma unroll
    for (int off = 4; off > 0; off >>= 1)
        #pragma unroll
        for (int i = 0; i < 4; ++i) {
            lsB[i] += __shfl_down(lsB[i], off);
            lqB[i] += __shfl_down(lqB[i], off);
        }
    if (kg == 0)
        #pragma unroll
        for (int i = 0; i < 4; ++i) {
            atomicAdd(&dsum[o0 + i], (double)lsB[i]);
            atomicAdd(&dsq[o0 + i], (double)lqB[i]);
        }
}

// ---------------- Stage 2 ----------------
constexpr int LDK2 = 68;  // 64 k + 4 pad

DEVI void s2_gatherT(int t, int bs, const float* xyz1, const float* xyz2,
                     const int* ni2, const float* f1, float* xT) {
    int b = bs >> 7;
    float cx = xyz2[bs * 3 + 0], cy = xyz2[bs * 3 + 1], cz = xyz2[bs * 3 + 2];
    for (int idx = t; idx < K2 * 134; idx += 512) {
        int k = idx / 134, c = idx - k * 134;
        int j = ni2[bs * K2 + k];
        const float* p1 = xyz1 + ((size_t)b * S1 + j) * 3;
        float v;
        if (c < 3)      v = p1[c] - (c == 0 ? cx : (c == 1 ? cy : cz));
        else if (c < 6) v = p1[c - 3];
        else            v = f1[((size_t)b * S1 + j) * 128 + (c - 6)];
        xT[c * LDK2 + k] = v;
    }
}

// Stats of y2a (C=134 -> O=128). Tile 4o x 4k; LDS 36.4K -> 4 blk/CU.
__global__ __launch_bounds__(512, 4)
void k_s2_statsA(const float* __restrict__ xyz1, const float* __restrict__ xyz2,
                 const int* __restrict__ ni2, const float* __restrict__ f1,
                 const float* __restrict__ w2aT,
                 double* __restrict__ dsum, double* __restrict__ dsq) {
    __shared__ float xT[134 * LDK2];   // 36.4 KB
    int t = threadIdx.x;
    int og = t >> 4, kg = t & 15;      // 32 x 16
    int o0 = og * 4, k0 = kg * 4;
    float ls[4] = {0.f, 0.f, 0.f, 0.f}, lq[4] = {0.f, 0.f, 0.f, 0.f};
    for (int bs = blockIdx.x; bs < Bb * S2; bs += gridDim.x) {
        __syncthreads();
        s2_gatherT(t, bs, xyz1, xyz2, ni2, f1, xT);
        __syncthreads();
        float acc[16];
        #pragma unroll
        for (int i = 0; i < 16; ++i) acc[i] = 0.f;
        for (int c = 0; c < 134; ++c) {
            float4 wv = *(const float4*)&w2aT[c * 128 + o0];
            float4 xv = *(const float4*)&xT[c * LDK2 + k0];
            float ws[4] = {wv.x, wv.y, wv.z, wv.w};
            float xs[4] = {xv.x, xv.y, xv.z, xv.w};
            #pragma unroll
            for (int i = 0; i < 4; ++i)
                #pragma unroll
                for (int j = 0; j < 4; ++j)
                    acc[i * 4 + j] = fmaf(ws[i], xs[j], acc[i * 4 + j]);
        }
        #pragma unroll
        for (int i = 0; i < 4; ++i)
            #pragma unroll
            for (int j = 0; j < 4; ++j) {
                float y = acc[i * 4 + j];
                ls[i] += y; lq[i] += y * y;
            }
    }
    #pragma unroll
    for (int off = 8; off > 0; off >>= 1)
        #pragma unroll
        for (int i = 0; i < 4; ++i) {
            ls[i] += __shfl_down(ls[i], off);
            lq[i] += __shfl_down(lq[i], off);
        }
    if (kg == 0)
        #pragma unroll
        for (int i = 0; i < 4; ++i) {
            atomicAdd(&dsum[o0 + i], (double)ls[i]);
            atomicAdd(&dsq[o0 + i], (double)lq[i]);
        }
}

// Main stage-2 — EXACT round-6 configuration, the measured best (620 us, VGPR 64,
// VALUBusy 70%). Rounds 7/8 launch-bounds/tile experiments both regressed (777/800):
// the compiler won't keep accB[64] in arch VGPRs regardless of bounds; (512,4)'s
// tight allocation empirically schedules best. Do not retune registers here.
__global__ __launch_bounds__(512, 4)
void k_s2_main(const float* __restrict__ xyz1, const float* __restrict__ xyz2,
               const int* __restrict__ ni2, const float* __restrict__ f1,
               const float* __restrict__ w2aT,
               const float* __restrict__ m2a, const float* __restrict__ s2a,
               const float* __restrict__ beta2a, const float* __restrict__ w2bT,
               double* __restrict__ dsum, double* __restrict__ dsq,
               float* __restrict__ gmx, float* __restrict__ gmn) {
    __shared__ float xT[134 * LDK2];    // 36.4 KB gather tile
    __shared__ float x2T[128 * LDK2];   // 34.8 KB x2 [c2][k]
    int t = threadIdx.x;
    int ogA = t >> 4, kgA = t & 15;    // A: 4o x 4k
    int o0A = ogA * 4, k0A = kgA * 4;
    int ogB = t >> 2, kgB = t & 3;     // B: 4o x 16k
    int o0B = ogB * 4, k0B = kgB * 16;
    float lsB[4] = {0.f, 0.f, 0.f, 0.f}, lqB[4] = {0.f, 0.f, 0.f, 0.f};
    for (int bs = blockIdx.x; bs < Bb * S2; bs += gridDim.x) {
        __syncthreads();
        s2_gatherT(t, bs, xyz1, xyz2, ni2, f1, xT);
        __syncthreads();
        // A: y2a tile
        float acc[16];
        #pragma unroll
        for (int i = 0; i < 16; ++i) acc[i] = 0.f;
        for (int c = 0; c < 134; ++c) {
            float4 wv = *(const float4*)&w2aT[c * 128 + o0A];
            float4 xv = *(const float4*)&xT[c * LDK2 + k0A];
            float ws[4] = {wv.x, wv.y, wv.z, wv.w};
            float xs[4] = {xv.x, xv.y, xv.z, xv.w};
            #pragma unroll
            for (int i = 0; i < 4; ++i)
                #pragma unroll
                for (int j = 0; j < 4; ++j)
                    acc[i * 4 + j] = fmaf(ws[i], xs[j], acc[i * 4 + j]);
        }
        float4 mam = *(const float4*)&m2a[o0A];
        float4 sam = *(const float4*)&s2a[o0A];
        float4 bam = *(const float4*)&beta2a[o0A];
        float ma[4] = {mam.x, mam.y, mam.z, mam.w};
        float sa[4] = {sam.x, sam.y, sam.z, sam.w};
        float ba[4] = {bam.x, bam.y, bam.z, bam.w};
        #pragma unroll
        for (int i = 0; i < 4; ++i) {
            float4 v;
            v.x = fmaxf((acc[i * 4 + 0] - ma[i]) * sa[i] + ba[i], 0.f);
            v.y = fmaxf((acc[i * 4 + 1] - ma[i]) * sa[i] + ba[i], 0.f);
            v.z = fmaxf((acc[i * 4 + 2] - ma[i]) * sa[i] + ba[i], 0.f);
            v.w = fmaxf((acc[i * 4 + 3] - ma[i]) * sa[i] + ba[i], 0.f);
            *(float4*)&x2T[(o0A + i) * LDK2 + k0A] = v;
        }
        __syncthreads();
        // B: y2b tile 4o x 16k; w2bT global broadcast (L2-hot)
        float accB[64];
        #pragma unroll
        for (int i = 0; i < 64; ++i) accB[i] = 0.f;
        for (int c = 0; c < 128; ++c) {
            float4 wv = *(const float4*)&w2bT[c * 512 + o0B];
            const float* xr = &x2T[c * LDK2 + k0B];
            float4 x0 = *(const float4*)(xr);
            float4 x1 = *(const float4*)(xr + 4);
            float4 x2 = *(const float4*)(xr + 8);
            float4 x3 = *(const float4*)(xr + 12);
            float ws[4] = {wv.x, wv.y, wv.z, wv.w};
            float xs[16] = {x0.x, x0.y, x0.z, x0.w, x1.x, x1.y, x1.z, x1.w,
                            x2.x, x2.y, x2.z, x2.w, x3.x, x3.y, x3.z, x3.w};
            #pragma unroll
            for (int i = 0; i < 4; ++i)
                #pragma unroll
                for (int j = 0; j < 16; ++j)
                    accB[i * 16 + j] = fmaf(ws[i], xs[j], accB[i * 16 + j]);
        }
        float mxB[4], mnB[4];
        #pragma unroll
        for (int i = 0; i < 4; ++i) {
            mxB[i] = -1e30f; mnB[i] = 1e30f;
            #pragma unroll
            for (int j = 0; j < 16; ++j) {
                float y = accB[i * 16 + j];
                lsB[i] += y; lqB[i] += y * y;
                mxB[i] = fmaxf(mxB[i], y); mnB[i] = fminf(mnB[i], y);
            }
        }
        #pragma unroll
        for (int off = 2; off > 0; off >>= 1)
            #pragma unroll
            for (int i = 0; i < 4; ++i) {
                mxB[i] = fmaxf(mxB[i], __shfl_down(mxB[i], off));
                mnB[i] = fminf(mnB[i], __shfl_down(mnB[i], off));
            }
        if (kgB == 0) {
            *(float4*)&gmx[(size_t)bs * 512 + o0B] = make_float4(mxB[0], mxB[1], mxB[2], mxB[3]);
            *(float4*)&gmn[(size_t)bs * 512 + o0B] = make_float4(mnB[0], mnB[1], mnB[2], mnB[3]);
        }
    }
    #pragma unroll
    for (int off = 2; off > 0; off >>= 1)
        #pragma unroll
        for (int i = 0; i < 4; ++i) {
            lsB[i] += __shfl_down(lsB[i], off);
            lqB[i] += __shfl_down(lqB[i], off);
        }
    if (kgB == 0)
        #pragma unroll
        for (int i = 0; i < 4; ++i) {
            atomicAdd(&dsum[o0B + i], (double)lsB[i]);
            atomicAdd(&dsq[o0B + i], (double)lqB[i]);
        }
}

// ---------------- Stage 3 ----------------
constexpr int X3_LD = 520;

__global__ __launch_bounds__(512)
void k_s3(const float* __restrict__ xyz2, const float* __restrict__ f2,
          const float* __restrict__ w3, double* __restrict__ dsum,
          double* __restrict__ dsq, float* __restrict__ gmx, float* __restrict__ gmn) {
    __shared__ float xt[16 * X3_LD];  // 33.3 KB
    int b = blockIdx.x >> 3, kc = blockIdx.x & 7;
    int t = threadIdx.x;  // = o
    for (int idx = t; idx < 16 * X3_LD; idx += 512) {
        int rr = idx / X3_LD, c = idx - rr * X3_LD;
        int row = b * S2 + kc * 16 + rr;
        float v;
        if (c < 3)        v = xyz2[row * 3 + c];
        else if (c < 515) v = f2[(size_t)row * 512 + (c - 3)];
        else              v = 0.f;
        xt[idx] = v;
    }
    __syncthreads();
    float acc[16];
    #pragma unroll
    for (int rr = 0; rr < 16; ++rr) acc[rr] = 0.f;
    for (int ct = 0; ct < 16; ++ct) {
        float wr[32];
        #pragma unroll
        for (int i = 0; i < 32; ++i) wr[i] = w3[(size_t)t * 515 + ct * 32 + i];
        #pragma unroll
        for (int rr = 0; rr < 16; ++rr) {
            const float* xr = &xt[rr * X3_LD + ct * 32];
            #pragma unroll
            for (int j = 0; j < 8; ++j) {
                float4 x = *(const float4*)(xr + 4 * j);
                acc[rr] = fmaf(x.x, wr[4 * j + 0], acc[rr]);
                acc[rr] = fmaf(x.y, wr[4 * j + 1], acc[rr]);
                acc[rr] = fmaf(x.z, wr[4 * j + 2], acc[rr]);
                acc[rr] = fmaf(x.w, wr[4 * j + 3], acc[rr]);
            }
        }
    }
    {
        float wr[8];
        #pragma unroll
        for (int i = 0; i < 8; ++i) wr[i] = (i < 3) ? w3[(size_t)t * 515 + 512 + i] : 0.f;
        #pragma unroll
        for (int rr = 0; rr < 16; ++rr) {
            const float* xr = &xt[rr * X3_LD + 512];
            #pragma unroll
            for (int j = 0; j < 2; ++j) {
                float4 x = *(const float4*)(xr + 4 * j);
                acc[rr] = fmaf(x.x, wr[4 * j + 0], acc[rr]);
                acc[rr] = fmaf(x.y, wr[4 * j + 1], acc[rr]);
                acc[rr] = fmaf(x.z, wr[4 * j + 2], acc[rr]);
                acc[rr] = fmaf(x.w, wr[4 * j + 3], acc[rr]);
            }
        }
    }
    float ls = 0.f, lsq = 0.f, mxv = -1e30f, mnv = 1e30f;
    #pragma unroll
    for (int rr = 0; rr < 16; ++rr) {
        float y = acc[rr];
        ls += y; lsq += y * y;
        mxv = fmaxf(mxv, y); mnv = fminf(mnv, y);
    }
    atomicAdd(&dsum[t], (double)ls);
    atomicAdd(&dsq[t], (double)lsq);
    gmx[(size_t)blockIdx.x * 512 + t] = mxv;
    gmn[(size_t)blockIdx.x * 512 + t] = mnv;
}

__global__ void k_apply3(const float* __restrict__ gmx, const float* __restrict__ gmn,
                         const float* __restrict__ m, const float* __restrict__ s,
                         const float* __restrict__ beta, float* __restrict__ out) {
    int i = blockIdx.x * blockDim.x + threadIdx.x;
    if (i >= Bb * 512) return;
    int b = i >> 9, o = i & 511;
    float mx = -1e30f, mn = 1e30f;
    for (int ch = 0; ch < 8; ++ch) {
        mx = fmaxf(mx, gmx[(size_t)(b * 8 + ch) * 512 + o]);
        mn = fminf(mn, gmn[(size_t)(b * 8 + ch) * 512 + o]);
    }
    float sc = s[o];
    float pick = (sc >= 0.f) ? mx : mn;
    out[i] = fmaxf((pick - m[o]) * sc + beta[o], 0.f);
}

static inline size_t align256(size_t x) { return (x + 255) & ~(size_t)255; }

extern "C" void kernel_launch(void* const* d_in, const int* in_sizes, int n_in,
                              void* d_out, int out_size, void* d_ws, size_t ws_size,
                              hipStream_t stream) {
    const float* pc  = (const float*)d_in[0];
    const float* w1a = (const float*)d_in[1];
    const float* g1a = (const float*)d_in[2];
    const float* b1a = (const float*)d_in[3];
    const float* w1b = (const float*)d_in[4];
    const float* g1b = (const float*)d_in[5];
    const float* b1b = (const float*)d_in[6];
    const float* w2a = (const float*)d_in[7];
    const float* g2a = (const float*)d_in[8];
    const float* b2a = (const float*)d_in[9];
    const float* w2b = (const float*)d_in[10];
    const float* g2b = (const float*)d_in[11];
    const float* b2b = (const float*)d_in[12];
    const float* w3  = (const float*)d_in[13];
    const float* g3  = (const float*)d_in[14];
    const float* b3  = (const float*)d_in[15];
    float* out = (float*)d_out;

    char* ws = (char*)d_ws;
    size_t off = 0;
    auto alloc = [&](size_t bytes) { void* p = ws + off; off += align256(bytes); return p; };

    float* xyz   = (float*)alloc(sizeof(float) * Bb * Nn * 3);
    float* xyz1  = (float*)alloc(sizeof(float) * Bb * S1 * 3);
    float* xyz2  = (float*)alloc(sizeof(float) * Bb * S2 * 3);
    int*   ni1   = (int*)alloc(sizeof(int) * Bb * S1 * K1);
    int*   ni2   = (int*)alloc(sizeof(int) * Bb * S2 * K2);
    float* gmx1  = (float*)alloc(sizeof(float) * (size_t)Bb * S1 * 128);  // f1 after apply
    float* gmn1  = (float*)alloc(sizeof(float) * (size_t)Bb * S1 * 128);
    float* gmx2  = (float*)alloc(sizeof(float) * (size_t)Bb * S2 * 512);  // f2 after apply
    float* gmn2  = (float*)alloc(sizeof(float) * (size_t)Bb * S2 * 512);
    float* gmx3  = (float*)alloc(sizeof(float) * 256 * 512);
    float* gmn3  = (float*)alloc(sizeof(float) * 256 * 512);
    float* w2aT  = (float*)alloc(sizeof(float) * 134 * 128);
    float* w2bT  = (float*)alloc(sizeof(float) * 128 * 512);
    // Stats arena: one contiguous block, zeroed ONCE in k_prep (was 5 zero launches).
    double* statz = (double*)alloc(sizeof(double) * 4096);
    double* dG    = statz;          // 27 (stage-1a moments)
    double* d1b_s = statz + 32;     // 128
    double* d1b_q = statz + 160;    // 128
    double* d2a_s = statz + 288;    // 128
    double* d2a_q = statz + 416;    // 128
    double* d2b_s = statz + 544;    // 512
    double* d2b_q = statz + 1056;   // 512
    double* d3_s  = statz + 1568;   // 512
    double* d3_q  = statz + 2080;   // 512
    float* m1a = (float*)alloc(sizeof(float) * 64);
    float* s1a = (float*)alloc(sizeof(float) * 64);
    float* m1b = (float*)alloc(sizeof(float) * 128);
    float* s1b = (float*)alloc(sizeof(float) * 128);
    float* m2a = (float*)alloc(sizeof(float) * 128);
    float* s2a = (float*)alloc(sizeof(float) * 128);
    float* m2b = (float*)alloc(sizeof(float) * 512);
    float* s2b = (float*)alloc(sizeof(float) * 512);
    float* m3  = (float*)alloc(sizeof(float) * 512);
    float* s3  = (float*)alloc(sizeof(float) * 512);
    float* f1 = gmx1;  // in-place apply
    float* f2 = gmx2;

    // ---- Stage 1 ----
    k_prep<<<(Bb * Nn + 255) / 256, 256, 0, stream>>>(pc, xyz, w2a, w2b, w2aT, w2bT, statz);
    k_fps_fast<8><<<Bb, 256, 0, stream>>>(xyz, S1, xyz1);
    k_ballquery_w<<<(Bb * S1) / 4, 256, 0, stream>>>(xyz, xyz1, Nn, S1, K1,
                                                     (float)(0.23 * 0.23), ni1);
    k_s1_moments<<<1024, 256, 0, stream>>>(xyz, xyz1, ni1, dG);
    k_fin1a<<<1, 64, 0, stream>>>(dG, w1a, g1a, m1a, s1a,
                                  1.0 / ((double)Bb * S1 * K1));
    k_s1_main<<<1024, 512, 0, stream>>>(xyz, xyz1, ni1, w1a, m1a, s1a, b1a, w1b,
                                        d1b_s, d1b_q, gmx1, gmn1);
    k_finalize<<<1, 128, 0, stream>>>(d1b_s, d1b_q, g1b, m1b, s1b, 128,
                                      1.0 / ((double)Bb * S1 * K1));
    {
        long long tot = (long long)Bb * S1 * 128;
        k_applyMM<<<(int)((tot + 255) / 256), 256, 0, stream>>>(gmx1, gmn1, m1b, s1b, b1b,
                                                                f1, tot, 128);
    }
    // ---- Stage 2 ----
    k_fps_fast<2><<<Bb, 256, 0, stream>>>(xyz1, S2, xyz2);
    k_ballquery_w<<<(Bb * S2) / 4, 256, 0, stream>>>(xyz1, xyz2, S1, S2, K2,
                                                     (float)(0.32 * 0.32), ni2);
    k_s2_statsA<<<1024, 512, 0, stream>>>(xyz1, xyz2, ni2, f1, w2aT, d2a_s, d2a_q);
    k_finalize<<<1, 128, 0, stream>>>(d2a_s, d2a_q, g2a, m2a, s2a, 128,
                                      1.0 / ((double)Bb * S2 * K2));
    k_s2_main<<<1024, 512, 0, stream>>>(xyz1, xyz2, ni2, f1, w2aT, m2a, s2a, b2a, w2bT,
                                        d2b_s, d2b_q, gmx2, gmn2);
    k_finalize<<<1, 512, 0, stream>>>(d2b_s, d2b_q, g2b, m2b, s2b, 512,
                                      1.0 / ((double)Bb * S2 * K2));
    {
        long long tot = (long long)Bb * S2 * 512;
        k_applyMM<<<(int)((tot + 255) / 256), 256, 0, stream>>>(gmx2, gmn2, m2b, s2b, b2b,
                                                                f2, tot, 512);
    }
    // ---- Stage 3 ----
    k_s3<<<256, 512, 0, stream>>>(xyz2, f2, w3, d3_s, d3_q, gmx3, gmn3);
    k_finalize<<<1, 512, 0, stream>>>(d3_s, d3_q, g3, m3, s3, 512,
                                      1.0 / ((double)Bb * S2));
    k_apply3<<<(Bb * 512 + 255) / 256, 256, 0, stream>>>(gmx3, gmn3, m3, s3, b3, out);
}